// Round 2
// baseline (3781.785 us; speedup 1.0000x reference)
//
#include <hip/hip_runtime.h>
#include <hip/hip_bf16.h>

// EquivariantInteractionBlock on MI355X (gfx950).
// Dual-dtype defensive version: a sniff kernel detects at runtime whether the
// float tensors are bf16 or f32 (low-half exponent statistics) and whether the
// index tensors are int32 or int64 (odd-word-zero pattern). All kernels branch
// wave-uniformly on those flags. MFMA core is bf16 either way (f32 inputs are
// converted during staging); aggregation is f32 via unsafeAtomicAdd into ws.

#define Hdim 128
#define Fdim 64
#define Mdim 16
#define TE   64    // edges (or nodes) per block tile
#define XLD  200   // LDS leading dim for [64][192] tile
#define YLD  136   // LDS leading dim for [64][128] tile
#define SLD  40    // LDS leading dim for sh [64][32] tile

typedef __attribute__((ext_vector_type(8))) short short8;
typedef __attribute__((ext_vector_type(4))) short short4v;
typedef __attribute__((ext_vector_type(4))) float float4v;

__device__ __forceinline__ float b2f(short s) {
    union { unsigned u; float f; } c;
    c.u = ((unsigned)(unsigned short)s) << 16;
    return c.f;
}
__device__ __forceinline__ short f2b(float f) {
    union { __hip_bfloat16 h; short s; } c;
    c.h = __float2bfloat16(f);
    return c.s;
}
// scalar float load from either bf16 or f32 tensor
__device__ __forceinline__ float ldf(const void* p, long i, int isbf) {
    return isbf ? b2f(((const short*)p)[i]) : ((const float*)p)[i];
}
// index load from either int32 or int64 tensor
__device__ __forceinline__ int ldi(const void* p, long i, int is64) {
    return is64 ? (int)((const long long*)p)[i] : ((const int*)p)[i];
}

// flags[0] = 1 if float tensors are bf16, 0 if f32
// flags[1] = 1 if index tensors are int64, 0 if int32
__global__ void ei_sniff_kernel(const unsigned* __restrict__ hw,
                                const unsigned* __restrict__ iw,
                                int* __restrict__ flags)
{
    __shared__ int cf[64], ci[64];
    const int t = threadIdx.x;
    int c1 = 0, c2 = 0;
#pragma unroll
    for (int k = 0; k < 4; ++k) {
        const unsigned w = hw[t + 64 * k];          // 32-bit word of h
        const unsigned e = (w >> 7) & 0xFFu;        // exponent field of LOW bf16 half
        c1 += (e >= 100u && e <= 140u) ? 1 : 0;     // sane randn exponent?
        const unsigned wi = iw[2 * (t + 64 * k) + 1]; // odd 32-bit word of edge_i
        c2 += (wi == 0u) ? 1 : 0;                   // int64 high halves are 0
    }
    cf[t] = c1; ci[t] = c2;
    __syncthreads();
    if (t == 0) {
        int s1 = 0, s2 = 0;
        for (int i = 0; i < 64; ++i) { s1 += cf[i]; s2 += ci[i]; }
        flags[0] = (s1 >= 192) ? 1 : 0;   // bf16: ~256/256; f32: ~41/256
        flags[1] = (s2 >= 200) ? 1 : 0;   // int64: 256/256 zeros; int32: ~0
    }
}

__global__ void ei_zero_kernel(float* __restrict__ p, int n4) {
    int i = blockIdx.x * blockDim.x + threadIdx.x;
    const int stride = gridDim.x * blockDim.x;
    float4v z;
    z[0] = z[1] = z[2] = z[3] = 0.f;
    for (; i < n4; i += stride) ((float4v*)p)[i] = z;
}

// Edge kernel: per 64-edge tile,
//   scalar_msg = silu([h_j|edge_feat] @ W1 + b1) @ W2 + b2 -> atomic agg_s (f32)
//   eq_msg     = (h_j @ W_in + b_in) * (sh @ W_tp)         -> atomic agg_q (f32)
// MFMA role-swap: A = W^T fragments (registers, persistent), B = X tile (LDS).
__global__ __launch_bounds__(256, 2)
void ei_edge_kernel(const void* __restrict__ hmat,
                    const void* __restrict__ efeat,
                    const void* __restrict__ shmat,
                    const void* __restrict__ edge_i,
                    const void* __restrict__ edge_j,
                    const void* __restrict__ W1,
                    const void* __restrict__ b1,
                    const void* __restrict__ W2,
                    const void* __restrict__ b2,
                    const void* __restrict__ Win,
                    const void* __restrict__ bin,
                    const void* __restrict__ Wtp,
                    float* __restrict__ agg_s,
                    float* __restrict__ agg_q,
                    const int* __restrict__ flags,
                    int ntiles)
{
    __shared__ alignas(16) short Xs[TE][XLD];  // [edge][k] k=0..191 ([h_j | edge_feat])
    __shared__ alignas(16) short Ys[TE][YLD];  // silu intermediate [edge][c1]
    __shared__ alignas(16) short Ss[TE][SLD];  // sh [edge][0..15], zeros [16..31]
    __shared__ int ids[TE];

    const int dtf = flags[0];   // 1=bf16 floats, 0=f32 floats
    const int dti = flags[1];   // 1=int64 indices, 0=int32

    const int tid  = threadIdx.x;
    const int lane = tid & 63;
    const int wv   = tid >> 6;
    const int q    = lane >> 4;
    const int ln   = lane & 15;
    const int mch0 = wv * 32;

    // one-time: zero all LDS tiles (covers pads; data cols are rewritten per tile)
    for (int i = tid; i < TE * XLD; i += 256) ((short*)Xs)[i] = 0;
    for (int i = tid; i < TE * YLD; i += 256) ((short*)Ys)[i] = 0;
    for (int i = tid; i < TE * SLD; i += 256) ((short*)Ss)[i] = 0;
    __syncthreads();

    // ---- persistent weight A-fragments: lane m = out-channel, k contiguous-8 ----
    short8 w1f[6][2], w2f[4][2], wif[4][2], wtf[2];
    float4v b1v[2], b2v[2], biv[2];
#pragma unroll
    for (int mt = 0; mt < 2; ++mt) {
        const int m = mch0 + mt * 16 + ln;
#pragma unroll
        for (int kc = 0; kc < 6; ++kc) {
            short8 t;
            const int k0 = kc * 32 + q * 8;
#pragma unroll
            for (int j = 0; j < 8; ++j) t[j] = dtf ? ((const short*)W1)[(long)(k0 + j) * Hdim + m]
                                                   : f2b(((const float*)W1)[(long)(k0 + j) * Hdim + m]);
            w1f[kc][mt] = t;
        }
#pragma unroll
        for (int kc = 0; kc < 4; ++kc) {
            short8 t, u;
            const int k0 = kc * 32 + q * 8;
#pragma unroll
            for (int j = 0; j < 8; ++j) {
                const long idx = (long)(k0 + j) * Hdim + m;
                t[j] = dtf ? ((const short*)W2)[idx]  : f2b(((const float*)W2)[idx]);
                u[j] = dtf ? ((const short*)Win)[idx] : f2b(((const float*)Win)[idx]);
            }
            w2f[kc][mt] = t;
            wif[kc][mt] = u;
        }
        {
            short8 t;
#pragma unroll
            for (int j = 0; j < 8; ++j) {
                const int k = q * 8 + j;
                t[j] = (k < Mdim) ? (dtf ? ((const short*)Wtp)[(long)k * Hdim + m]
                                         : f2b(((const float*)Wtp)[(long)k * Hdim + m]))
                                  : (short)0;
            }
            wtf[mt] = t;
        }
        const int cb = mch0 + mt * 16 + q * 4;
#pragma unroll
        for (int r = 0; r < 4; ++r) {
            b1v[mt][r] = ldf(b1, cb + r, dtf);
            b2v[mt][r] = ldf(b2, cb + r, dtf);
            biv[mt][r] = ldf(bin, cb + r, dtf);
        }
    }

    const int e_loc = tid >> 2;   // 0..63
    const int part  = tid & 3;    // 0..3

    for (int tile = blockIdx.x; tile < ntiles; tile += gridDim.x) {
        // ---- stage: gather h[edge_j], stream edge_feat & sh into LDS ----
        {
            const int edge = tile * TE + e_loc;   // E % 64 == 0
            const int j = ldi(edge_j, edge, dti);
            if (dtf) {
                const uint4* hsrc = (const uint4*)((const short*)hmat + (long)j * Hdim);
                uint4* xd = (uint4*)&Xs[e_loc][part * 32];
#pragma unroll
                for (int i = 0; i < 4; ++i) xd[i] = hsrc[part * 4 + i];
                const uint4* fsrc = (const uint4*)((const short*)efeat + (long)edge * Fdim);
                uint4* fd = (uint4*)&Xs[e_loc][Hdim + part * 16];
                fd[0] = fsrc[part * 2 + 0];
                fd[1] = fsrc[part * 2 + 1];
                if (part == 0) {
                    const uint4* ssrc = (const uint4*)((const short*)shmat + (long)edge * Mdim);
                    ((uint4*)&Ss[e_loc][0])[0] = ssrc[0];
                    ((uint4*)&Ss[e_loc][0])[1] = ssrc[1];
                }
            } else {
                const float4v* hs = (const float4v*)((const float*)hmat + (long)j * Hdim + part * 32);
#pragma unroll
                for (int c = 0; c < 4; ++c) {
                    const float4v v0 = hs[2 * c], v1 = hs[2 * c + 1];
                    short8 t;
#pragma unroll
                    for (int r = 0; r < 4; ++r) { t[r] = f2b(v0[r]); t[4 + r] = f2b(v1[r]); }
                    *(short8*)&Xs[e_loc][part * 32 + c * 8] = t;
                }
                const float4v* fs = (const float4v*)((const float*)efeat + (long)edge * Fdim + part * 16);
#pragma unroll
                for (int c = 0; c < 2; ++c) {
                    const float4v v0 = fs[2 * c], v1 = fs[2 * c + 1];
                    short8 t;
#pragma unroll
                    for (int r = 0; r < 4; ++r) { t[r] = f2b(v0[r]); t[4 + r] = f2b(v1[r]); }
                    *(short8*)&Xs[e_loc][Hdim + part * 16 + c * 8] = t;
                }
                if (part == 0) {
                    const float4v* ss = (const float4v*)((const float*)shmat + (long)edge * Mdim);
#pragma unroll
                    for (int c = 0; c < 2; ++c) {
                        const float4v v0 = ss[2 * c], v1 = ss[2 * c + 1];
                        short8 t;
#pragma unroll
                        for (int r = 0; r < 4; ++r) { t[r] = f2b(v0[r]); t[4 + r] = f2b(v1[r]); }
                        *(short8*)&Ss[e_loc][c * 8] = t;
                    }
                }
            }
            // Ss[16..31] stays zero from the one-time memset (never overwritten)
            if (tid < TE) ids[tid] = ldi(edge_i, tile * TE + tid, dti);
        }
        __syncthreads();

        // ---- GEMM1: Y = silu(X @ W1 + b1), K = 192 ----
        float4v a1[2][4] = {};
#pragma unroll
        for (int kc = 0; kc < 6; ++kc) {
            short8 xb[4];
#pragma unroll
            for (int nt = 0; nt < 4; ++nt)
                xb[nt] = *(const short8*)&Xs[nt * 16 + ln][kc * 32 + q * 8];
#pragma unroll
            for (int nt = 0; nt < 4; ++nt)
#pragma unroll
                for (int mt = 0; mt < 2; ++mt)
                    a1[mt][nt] = __builtin_amdgcn_mfma_f32_16x16x32_bf16(
                        w1f[kc][mt], xb[nt], a1[mt][nt], 0, 0, 0);
        }
#pragma unroll
        for (int mt = 0; mt < 2; ++mt)
#pragma unroll
            for (int nt = 0; nt < 4; ++nt) {
                short4v p;
#pragma unroll
                for (int r = 0; r < 4; ++r) {
                    const float y = a1[mt][nt][r] + b1v[mt][r];
                    const float s = y / (1.f + __expf(-y));   // silu
                    p[r] = f2b(s);
                }
                *(short4v*)&Ys[nt * 16 + ln][mch0 + mt * 16 + q * 4] = p;
            }
        __syncthreads();

        // ---- GEMM2: scalar_msg = Y @ W2 + b2, K = 128 ----
        float4v a2[2][4] = {};
#pragma unroll
        for (int kc = 0; kc < 4; ++kc) {
            short8 yb[4];
#pragma unroll
            for (int nt = 0; nt < 4; ++nt)
                yb[nt] = *(const short8*)&Ys[nt * 16 + ln][kc * 32 + q * 8];
#pragma unroll
            for (int nt = 0; nt < 4; ++nt)
#pragma unroll
                for (int mt = 0; mt < 2; ++mt)
                    a2[mt][nt] = __builtin_amdgcn_mfma_f32_16x16x32_bf16(
                        w2f[kc][mt], yb[nt], a2[mt][nt], 0, 0, 0);
        }
#pragma unroll
        for (int mt = 0; mt < 2; ++mt)
#pragma unroll
            for (int nt = 0; nt < 4; ++nt) {
                const int node = ids[nt * 16 + ln];
                float* dst = agg_s + (long)node * Hdim + mch0 + mt * 16 + q * 4;
#pragma unroll
                for (int r = 0; r < 4; ++r)
                    unsafeAtomicAdd(dst + r, a2[mt][nt][r] + b2v[mt][r]);
            }

        // ---- GEMM3: eq_in = h_j @ W_in + b_in (K=128); tp = sh @ W_tp ----
        float4v a3[2][4] = {};
        float4v at[2][4] = {};
#pragma unroll
        for (int kc = 0; kc < 4; ++kc) {
            short8 xb[4];
#pragma unroll
            for (int nt = 0; nt < 4; ++nt)
                xb[nt] = *(const short8*)&Xs[nt * 16 + ln][kc * 32 + q * 8];
#pragma unroll
            for (int nt = 0; nt < 4; ++nt)
#pragma unroll
                for (int mt = 0; mt < 2; ++mt)
                    a3[mt][nt] = __builtin_amdgcn_mfma_f32_16x16x32_bf16(
                        wif[kc][mt], xb[nt], a3[mt][nt], 0, 0, 0);
        }
        {
            short8 sb[4];
#pragma unroll
            for (int nt = 0; nt < 4; ++nt)
                sb[nt] = *(const short8*)&Ss[nt * 16 + ln][q * 8];
#pragma unroll
            for (int nt = 0; nt < 4; ++nt)
#pragma unroll
                for (int mt = 0; mt < 2; ++mt)
                    at[mt][nt] = __builtin_amdgcn_mfma_f32_16x16x32_bf16(
                        wtf[mt], sb[nt], at[mt][nt], 0, 0, 0);
        }
#pragma unroll
        for (int mt = 0; mt < 2; ++mt)
#pragma unroll
            for (int nt = 0; nt < 4; ++nt) {
                const int node = ids[nt * 16 + ln];
                float* dst = agg_q + (long)node * Hdim + mch0 + mt * 16 + q * 4;
#pragma unroll
                for (int r = 0; r < 4; ++r)
                    unsafeAtomicAdd(dst + r,
                        (a3[mt][nt][r] + biv[mt][r]) * at[mt][nt][r]);
            }
        __syncthreads();
    }
}

// Node kernel: h_new = h + agg_s @ W_up + b_up ;
//              gate = sigmoid(h_new @ W_gate + b_gate) ; h_eq_new = h_eq + agg_q * gate
__global__ __launch_bounds__(256, 2)
void ei_node_kernel(const void* __restrict__ hmat,
                    const void* __restrict__ heq,
                    const void* __restrict__ Wup,
                    const void* __restrict__ bup,
                    const void* __restrict__ Wg,
                    const void* __restrict__ bg,
                    const float* __restrict__ agg_s,
                    const float* __restrict__ agg_q,
                    void* __restrict__ outp,
                    const int* __restrict__ flags,
                    int N)
{
    __shared__ alignas(16) short Xa[TE][YLD];
    __shared__ alignas(16) short Yh[TE][YLD];

    const int dtf = flags[0];

    const int tid  = threadIdx.x;
    const int lane = tid & 63;
    const int wv   = tid >> 6;
    const int q    = lane >> 4;
    const int ln   = lane & 15;
    const int mch0 = wv * 32;

    short* outh_b = (short*)outp;
    short* outq_b = outh_b + (long)N * Hdim;
    float* outh_f = (float*)outp;
    float* outq_f = outh_f + (long)N * Hdim;

    short8 wuf[4][2], wgf[4][2];
    float4v buv[2], bgv[2];
#pragma unroll
    for (int mt = 0; mt < 2; ++mt) {
        const int m = mch0 + mt * 16 + ln;
#pragma unroll
        for (int kc = 0; kc < 4; ++kc) {
            short8 t, u;
            const int k0 = kc * 32 + q * 8;
#pragma unroll
            for (int j = 0; j < 8; ++j) {
                const long idx = (long)(k0 + j) * Hdim + m;
                t[j] = dtf ? ((const short*)Wup)[idx] : f2b(((const float*)Wup)[idx]);
                u[j] = dtf ? ((const short*)Wg)[idx]  : f2b(((const float*)Wg)[idx]);
            }
            wuf[kc][mt] = t;
            wgf[kc][mt] = u;
        }
        const int cb = mch0 + mt * 16 + q * 4;
#pragma unroll
        for (int r = 0; r < 4; ++r) {
            buv[mt][r] = ldf(bup, cb + r, dtf);
            bgv[mt][r] = ldf(bg, cb + r, dtf);
        }
    }

    const int e_loc = tid >> 2;
    const int part  = tid & 3;
    const int nb    = blockIdx.x * TE;

    // stage bf16(agg_s) tile (zeros for tail rows) via vector stores (no UB cast)
    {
        const int node = nb + e_loc;
        if (node < N) {
            const float4v* src = (const float4v*)(agg_s + (long)node * Hdim + part * 32);
#pragma unroll
            for (int c = 0; c < 4; ++c) {
                const float4v v0 = src[2 * c], v1 = src[2 * c + 1];
                short8 t;
#pragma unroll
                for (int r = 0; r < 4; ++r) { t[r] = f2b(v0[r]); t[4 + r] = f2b(v1[r]); }
                *(short8*)&Xa[e_loc][part * 32 + c * 8] = t;
            }
        } else {
            short8 z = {};
#pragma unroll
            for (int c = 0; c < 4; ++c)
                *(short8*)&Xa[e_loc][part * 32 + c * 8] = z;
        }
    }
    __syncthreads();

    // GEMM: agg_s @ W_up
    float4v au[2][4] = {};
#pragma unroll
    for (int kc = 0; kc < 4; ++kc) {
        short8 ab[4];
#pragma unroll
        for (int nt = 0; nt < 4; ++nt)
            ab[nt] = *(const short8*)&Xa[nt * 16 + ln][kc * 32 + q * 8];
#pragma unroll
        for (int nt = 0; nt < 4; ++nt)
#pragma unroll
            for (int mt = 0; mt < 2; ++mt)
                au[mt][nt] = __builtin_amdgcn_mfma_f32_16x16x32_bf16(
                    wuf[kc][mt], ab[nt], au[mt][nt], 0, 0, 0);
    }
    // h_new epilogue: write output + stage bf16(h_new) for gate GEMM
#pragma unroll
    for (int mt = 0; mt < 2; ++mt)
#pragma unroll
        for (int nt = 0; nt < 4; ++nt) {
            const int node = nb + nt * 16 + ln;
            const int ch = mch0 + mt * 16 + q * 4;
            short4v p;
            if (node < N) {
                float hv[4];
                if (dtf) {
                    const short4v x = *(const short4v*)((const short*)hmat + (long)node * Hdim + ch);
#pragma unroll
                    for (int r = 0; r < 4; ++r) hv[r] = b2f(x[r]);
                } else {
                    const float4v x = *(const float4v*)((const float*)hmat + (long)node * Hdim + ch);
#pragma unroll
                    for (int r = 0; r < 4; ++r) hv[r] = x[r];
                }
                float4v o;
#pragma unroll
                for (int r = 0; r < 4; ++r) {
                    o[r] = hv[r] + au[mt][nt][r] + buv[mt][r];
                    p[r] = f2b(o[r]);
                }
                if (dtf) *(short4v*)(outh_b + (long)node * Hdim + ch) = p;
                else     *(float4v*)(outh_f + (long)node * Hdim + ch) = o;
            } else {
#pragma unroll
                for (int r = 0; r < 4; ++r) p[r] = 0;
            }
            *(short4v*)&Yh[nt * 16 + ln][ch] = p;
        }
    __syncthreads();

    // GEMM: h_new @ W_gate ; h_eq_new epilogue
    float4v ag[2][4] = {};
#pragma unroll
    for (int kc = 0; kc < 4; ++kc) {
        short8 yb[4];
#pragma unroll
        for (int nt = 0; nt < 4; ++nt)
            yb[nt] = *(const short8*)&Yh[nt * 16 + ln][kc * 32 + q * 8];
#pragma unroll
        for (int nt = 0; nt < 4; ++nt)
#pragma unroll
            for (int mt = 0; mt < 2; ++mt)
                ag[mt][nt] = __builtin_amdgcn_mfma_f32_16x16x32_bf16(
                    wgf[kc][mt], yb[nt], ag[mt][nt], 0, 0, 0);
    }
#pragma unroll
    for (int mt = 0; mt < 2; ++mt)
#pragma unroll
        for (int nt = 0; nt < 4; ++nt) {
            const int node = nb + nt * 16 + ln;
            if (node >= N) continue;
            const int ch = mch0 + mt * 16 + q * 4;
            const float4v aq = *(const float4v*)(agg_q + (long)node * Hdim + ch);
            float hev[4];
            if (dtf) {
                const short4v x = *(const short4v*)((const short*)heq + (long)node * Hdim + ch);
#pragma unroll
                for (int r = 0; r < 4; ++r) hev[r] = b2f(x[r]);
            } else {
                const float4v x = *(const float4v*)((const float*)heq + (long)node * Hdim + ch);
#pragma unroll
                for (int r = 0; r < 4; ++r) hev[r] = x[r];
            }
            short4v p;
            float4v o;
#pragma unroll
            for (int r = 0; r < 4; ++r) {
                const float g = 1.f / (1.f + __expf(-(ag[mt][nt][r] + bgv[mt][r])));
                o[r] = hev[r] + aq[r] * g;
                p[r] = f2b(o[r]);
            }
            if (dtf) *(short4v*)(outq_b + (long)node * Hdim + ch) = p;
            else     *(float4v*)(outq_f + (long)node * Hdim + ch) = o;
        }
}

extern "C" void kernel_launch(void* const* d_in, const int* in_sizes, int n_in,
                              void* d_out, int out_size, void* d_ws, size_t ws_size,
                              hipStream_t stream)
{
    (void)n_in; (void)out_size; (void)ws_size;
    const void* hmat  = d_in[0];
    const void* heq   = d_in[1];
    const void* efeat = d_in[2];
    const void* shm   = d_in[3];
    const void* ei    = d_in[4];
    const void* ej    = d_in[5];
    const void* Win   = d_in[6];
    const void* bin   = d_in[7];
    const void* Wg    = d_in[8];
    const void* bg    = d_in[9];
    const void* W1    = d_in[10];
    const void* b1    = d_in[11];
    const void* W2    = d_in[12];
    const void* b2    = d_in[13];
    const void* Wup   = d_in[14];
    const void* bup   = d_in[15];
    const void* Wtp   = d_in[16];

    const int N = in_sizes[0] / Hdim;
    const int E = in_sizes[2] / Fdim;

    float* agg_s = (float*)d_ws;                  // [N,128] f32
    float* agg_q = agg_s + (long)N * Hdim;        // [N,128] f32
    int* flags = (int*)((char*)d_ws + (size_t)2 * N * Hdim * sizeof(float));

    ei_sniff_kernel<<<1, 64, 0, stream>>>((const unsigned*)hmat, (const unsigned*)ei, flags);

    const int n4 = N * Hdim * 2 / 4;
    ei_zero_kernel<<<4096, 256, 0, stream>>>((float*)d_ws, n4);

    const int ntiles = E / TE;                    // E = 1e6 -> 15625 exact
    ei_edge_kernel<<<1024, 256, 0, stream>>>(hmat, efeat, shm, ei, ej,
                                             W1, b1, W2, b2, Win, bin, Wtp,
                                             agg_s, agg_q, flags, ntiles);

    const int nblocks = (N + TE - 1) / TE;
    ei_node_kernel<<<nblocks, 256, 0, stream>>>(hmat, heq, Wup, bup, Wg, bg,
                                                agg_s, agg_q, d_out, flags, N);
}

// Round 3
// 1352.251 us; speedup vs baseline: 2.7967x; 2.7967x over previous
//
#include <hip/hip_runtime.h>
#include <hip/hip_bf16.h>

// EquivariantInteractionBlock on MI355X (gfx950).
// R3: replace f32 atomic scatter-add (TCC atomic-throughput bound, 76 G/s wall)
// with edge sort (hist/scan/scatter) + sorted bf16 message streaming + per-node
// contiguous gather-reduce fused with the node GEMMs. Falls back to the R2
// atomic path if ws_size < ~517 MB. Dual-dtype sniff kept (bf16/f32, i32/i64).

#define Hdim 128
#define Fdim 64
#define Mdim 16
#define TE   64    // edges (or nodes) per block tile
#define XLD  200   // LDS leading dim for [64][192] tile
#define YLD  136   // LDS leading dim for [64][128] tile
#define SLD  40    // LDS leading dim for sh [64][32] tile
#define QLD  132   // LDS leading dim for f32 [64][128] tile

typedef __attribute__((ext_vector_type(8))) short short8;
typedef __attribute__((ext_vector_type(4))) short short4v;
typedef __attribute__((ext_vector_type(4))) float float4v;

__device__ __forceinline__ float b2f(short s) {
    union { unsigned u; float f; } c;
    c.u = ((unsigned)(unsigned short)s) << 16;
    return c.f;
}
__device__ __forceinline__ short f2b(float f) {
    union { __hip_bfloat16 h; short s; } c;
    c.h = __float2bfloat16(f);
    return c.s;
}
__device__ __forceinline__ float ldf(const void* p, long i, int isbf) {
    return isbf ? b2f(((const short*)p)[i]) : ((const float*)p)[i];
}
__device__ __forceinline__ int ldi(const void* p, long i, int is64) {
    return is64 ? (int)((const long long*)p)[i] : ((const int*)p)[i];
}

// flags[0] = 1 if float tensors are bf16, 0 if f32
// flags[1] = 1 if index tensors are int64, 0 if int32
__global__ void ei_sniff_kernel(const unsigned* __restrict__ hw,
                                const unsigned* __restrict__ iw,
                                int* __restrict__ flags)
{
    __shared__ int cf[64], ci[64];
    const int t = threadIdx.x;
    int c1 = 0, c2 = 0;
#pragma unroll
    for (int k = 0; k < 4; ++k) {
        const unsigned w = hw[t + 64 * k];
        const unsigned e = (w >> 7) & 0xFFu;
        c1 += (e >= 100u && e <= 140u) ? 1 : 0;
        const unsigned wi = iw[2 * (t + 64 * k) + 1];
        c2 += (wi == 0u) ? 1 : 0;
    }
    cf[t] = c1; ci[t] = c2;
    __syncthreads();
    if (t == 0) {
        int s1 = 0, s2 = 0;
        for (int i = 0; i < 64; ++i) { s1 += cf[i]; s2 += ci[i]; }
        flags[0] = (s1 >= 192) ? 1 : 0;
        flags[1] = (s2 >= 200) ? 1 : 0;
    }
}

// ---------------- sort path: hist -> scan -> scatter ----------------

__global__ void ei_hist_kernel(const void* __restrict__ edge_i,
                               int* __restrict__ hist,
                               const int* __restrict__ flags, int E_)
{
    const int dti = flags[1];
    int i = blockIdx.x * blockDim.x + threadIdx.x;
    const int stride = gridDim.x * blockDim.x;
    for (; i < E_; i += stride) atomicAdd(&hist[ldi(edge_i, i, dti)], 1);
}

// 1 block, 1024 threads. hist doubles as cursor output (row starts).
__global__ void ei_scan_kernel(int* __restrict__ hist,
                               int* __restrict__ rs, int N_, int E_)
{
    __shared__ int buf[1024];
    const int t = threadIdx.x;
    const int chunk = (N_ + 1023) >> 10;
    const int base = t * chunk;
    int s = 0;
    for (int i = 0; i < chunk; ++i) {
        const int idx = base + i;
        if (idx < N_) s += hist[idx];
    }
    buf[t] = s;
    __syncthreads();
    for (int d = 1; d < 1024; d <<= 1) {
        const int v = (t >= d) ? buf[t - d] : 0;
        __syncthreads();
        buf[t] += v;
        __syncthreads();
    }
    int run = buf[t] - s;   // exclusive prefix
    for (int i = 0; i < chunk; ++i) {
        const int idx = base + i;
        if (idx >= N_) break;
        const int h = hist[idx];
        rs[idx] = run;
        hist[idx] = run;    // becomes scatter cursor
        run += h;
    }
    if (t == 0) rs[N_] = E_;
}

__global__ void ei_scatter_kernel(const void* __restrict__ edge_i,
                                  int* __restrict__ cur,
                                  int* __restrict__ perm,
                                  const int* __restrict__ flags, int E_)
{
    const int dti = flags[1];
    int i = blockIdx.x * blockDim.x + threadIdx.x;
    const int stride = gridDim.x * blockDim.x;
    for (; i < E_; i += stride) {
        const int c = ldi(edge_i, i, dti);
        const int p = atomicAdd(&cur[c], 1);
        perm[p] = i;
    }
}

// ---------------- sorted edge kernel: messages -> bf16 streams ----------------
// For sorted slot es = tile*64+row, edge e = perm[es]:
//   msg_s[es] = silu([h_j|edge_feat] @ W1 + b1) @ W2 + b2
//   msg_q[es] = (h_j @ W_in + b_in) * (sh @ W_tp)
__global__ __launch_bounds__(256, 2)
void ei_edge_sorted(const void* __restrict__ hmat,
                    const void* __restrict__ efeat,
                    const void* __restrict__ shmat,
                    const void* __restrict__ edge_j,
                    const int*  __restrict__ perm,
                    const void* __restrict__ W1,
                    const void* __restrict__ b1,
                    const void* __restrict__ W2,
                    const void* __restrict__ b2,
                    const void* __restrict__ Win,
                    const void* __restrict__ bin,
                    const void* __restrict__ Wtp,
                    short* __restrict__ msg_s,
                    short* __restrict__ msg_q,
                    const int* __restrict__ flags,
                    int ntiles)
{
    __shared__ alignas(16) short Xs[TE][XLD];
    __shared__ alignas(16) short Ys[TE][YLD];
    __shared__ alignas(16) short Ss[TE][SLD];

    const int dtf = flags[0];
    const int dti = flags[1];

    const int tid  = threadIdx.x;
    const int lane = tid & 63;
    const int wv   = tid >> 6;
    const int q    = lane >> 4;
    const int ln   = lane & 15;
    const int mch0 = wv * 32;

    for (int i = tid; i < TE * XLD; i += 256) ((short*)Xs)[i] = 0;
    for (int i = tid; i < TE * YLD; i += 256) ((short*)Ys)[i] = 0;
    for (int i = tid; i < TE * SLD; i += 256) ((short*)Ss)[i] = 0;
    __syncthreads();

    short8 w1f[6][2], w2f[4][2], wif[4][2], wtf[2];
    float4v b1v[2], b2v[2], biv[2];
#pragma unroll
    for (int mt = 0; mt < 2; ++mt) {
        const int m = mch0 + mt * 16 + ln;
#pragma unroll
        for (int kc = 0; kc < 6; ++kc) {
            short8 t;
            const int k0 = kc * 32 + q * 8;
#pragma unroll
            for (int j = 0; j < 8; ++j) t[j] = dtf ? ((const short*)W1)[(long)(k0 + j) * Hdim + m]
                                                   : f2b(((const float*)W1)[(long)(k0 + j) * Hdim + m]);
            w1f[kc][mt] = t;
        }
#pragma unroll
        for (int kc = 0; kc < 4; ++kc) {
            short8 t, u;
            const int k0 = kc * 32 + q * 8;
#pragma unroll
            for (int j = 0; j < 8; ++j) {
                const long idx = (long)(k0 + j) * Hdim + m;
                t[j] = dtf ? ((const short*)W2)[idx]  : f2b(((const float*)W2)[idx]);
                u[j] = dtf ? ((const short*)Win)[idx] : f2b(((const float*)Win)[idx]);
            }
            w2f[kc][mt] = t;
            wif[kc][mt] = u;
        }
        {
            short8 t;
#pragma unroll
            for (int j = 0; j < 8; ++j) {
                const int k = q * 8 + j;
                t[j] = (k < Mdim) ? (dtf ? ((const short*)Wtp)[(long)k * Hdim + m]
                                         : f2b(((const float*)Wtp)[(long)k * Hdim + m]))
                                  : (short)0;
            }
            wtf[mt] = t;
        }
        const int cb = mch0 + mt * 16 + q * 4;
#pragma unroll
        for (int r = 0; r < 4; ++r) {
            b1v[mt][r] = ldf(b1, cb + r, dtf);
            b2v[mt][r] = ldf(b2, cb + r, dtf);
            biv[mt][r] = ldf(bin, cb + r, dtf);
        }
    }

    const int e_loc = tid >> 2;
    const int part  = tid & 3;

    for (int tile = blockIdx.x; tile < ntiles; tile += gridDim.x) {
        // ---- stage (gather by perm) ----
        {
            const int es = tile * TE + e_loc;       // sorted slot; E % 64 == 0
            const int e  = perm[es];
            const int j  = ldi(edge_j, e, dti);
            if (dtf) {
                const uint4* hsrc = (const uint4*)((const short*)hmat + (long)j * Hdim);
                uint4* xd = (uint4*)&Xs[e_loc][part * 32];
#pragma unroll
                for (int i = 0; i < 4; ++i) xd[i] = hsrc[part * 4 + i];
                const uint4* fsrc = (const uint4*)((const short*)efeat + (long)e * Fdim);
                uint4* fd = (uint4*)&Xs[e_loc][Hdim + part * 16];
                fd[0] = fsrc[part * 2 + 0];
                fd[1] = fsrc[part * 2 + 1];
                if (part == 0) {
                    const uint4* ssrc = (const uint4*)((const short*)shmat + (long)e * Mdim);
                    ((uint4*)&Ss[e_loc][0])[0] = ssrc[0];
                    ((uint4*)&Ss[e_loc][0])[1] = ssrc[1];
                }
            } else {
                const float4v* hs = (const float4v*)((const float*)hmat + (long)j * Hdim + part * 32);
#pragma unroll
                for (int c = 0; c < 4; ++c) {
                    const float4v v0 = hs[2 * c], v1 = hs[2 * c + 1];
                    short8 t;
#pragma unroll
                    for (int r = 0; r < 4; ++r) { t[r] = f2b(v0[r]); t[4 + r] = f2b(v1[r]); }
                    *(short8*)&Xs[e_loc][part * 32 + c * 8] = t;
                }
                const float4v* fs = (const float4v*)((const float*)efeat + (long)e * Fdim + part * 16);
#pragma unroll
                for (int c = 0; c < 2; ++c) {
                    const float4v v0 = fs[2 * c], v1 = fs[2 * c + 1];
                    short8 t;
#pragma unroll
                    for (int r = 0; r < 4; ++r) { t[r] = f2b(v0[r]); t[4 + r] = f2b(v1[r]); }
                    *(short8*)&Xs[e_loc][Hdim + part * 16 + c * 8] = t;
                }
                if (part == 0) {
                    const float4v* ss = (const float4v*)((const float*)shmat + (long)e * Mdim);
#pragma unroll
                    for (int c = 0; c < 2; ++c) {
                        const float4v v0 = ss[2 * c], v1 = ss[2 * c + 1];
                        short8 t;
#pragma unroll
                        for (int r = 0; r < 4; ++r) { t[r] = f2b(v0[r]); t[4 + r] = f2b(v1[r]); }
                        *(short8*)&Ss[e_loc][c * 8] = t;
                    }
                }
            }
        }
        __syncthreads();

        // ---- GEMM1: Y = silu(X @ W1 + b1), K = 192 ----
        float4v a1[2][4] = {};
#pragma unroll
        for (int kc = 0; kc < 6; ++kc) {
            short8 xb[4];
#pragma unroll
            for (int nt = 0; nt < 4; ++nt)
                xb[nt] = *(const short8*)&Xs[nt * 16 + ln][kc * 32 + q * 8];
#pragma unroll
            for (int nt = 0; nt < 4; ++nt)
#pragma unroll
                for (int mt = 0; mt < 2; ++mt)
                    a1[mt][nt] = __builtin_amdgcn_mfma_f32_16x16x32_bf16(
                        w1f[kc][mt], xb[nt], a1[mt][nt], 0, 0, 0);
        }
#pragma unroll
        for (int mt = 0; mt < 2; ++mt)
#pragma unroll
            for (int nt = 0; nt < 4; ++nt) {
                short4v p;
#pragma unroll
                for (int r = 0; r < 4; ++r) {
                    const float y = a1[mt][nt][r] + b1v[mt][r];
                    const float s = y / (1.f + __expf(-y));
                    p[r] = f2b(s);
                }
                *(short4v*)&Ys[nt * 16 + ln][mch0 + mt * 16 + q * 4] = p;
            }
        __syncthreads();

        // ---- GEMM2: scalar_msg = Y @ W2 + b2 -> msg_s (coalesced bf16) ----
        float4v a2[2][4] = {};
#pragma unroll
        for (int kc = 0; kc < 4; ++kc) {
            short8 yb[4];
#pragma unroll
            for (int nt = 0; nt < 4; ++nt)
                yb[nt] = *(const short8*)&Ys[nt * 16 + ln][kc * 32 + q * 8];
#pragma unroll
            for (int nt = 0; nt < 4; ++nt)
#pragma unroll
                for (int mt = 0; mt < 2; ++mt)
                    a2[mt][nt] = __builtin_amdgcn_mfma_f32_16x16x32_bf16(
                        w2f[kc][mt], yb[nt], a2[mt][nt], 0, 0, 0);
        }
#pragma unroll
        for (int mt = 0; mt < 2; ++mt)
#pragma unroll
            for (int nt = 0; nt < 4; ++nt) {
                const long es = (long)tile * TE + nt * 16 + ln;
                short4v p;
#pragma unroll
                for (int r = 0; r < 4; ++r) p[r] = f2b(a2[mt][nt][r] + b2v[mt][r]);
                *(short4v*)(msg_s + es * Hdim + mch0 + mt * 16 + q * 4) = p;
            }

        // ---- GEMM3: eq_msg = (h_j @ W_in + b_in) * (sh @ W_tp) -> msg_q ----
        float4v a3[2][4] = {};
        float4v at[2][4] = {};
#pragma unroll
        for (int kc = 0; kc < 4; ++kc) {
            short8 xb[4];
#pragma unroll
            for (int nt = 0; nt < 4; ++nt)
                xb[nt] = *(const short8*)&Xs[nt * 16 + ln][kc * 32 + q * 8];
#pragma unroll
            for (int nt = 0; nt < 4; ++nt)
#pragma unroll
                for (int mt = 0; mt < 2; ++mt)
                    a3[mt][nt] = __builtin_amdgcn_mfma_f32_16x16x32_bf16(
                        wif[kc][mt], xb[nt], a3[mt][nt], 0, 0, 0);
        }
        {
            short8 sb[4];
#pragma unroll
            for (int nt = 0; nt < 4; ++nt)
                sb[nt] = *(const short8*)&Ss[nt * 16 + ln][q * 8];
#pragma unroll
            for (int nt = 0; nt < 4; ++nt)
#pragma unroll
                for (int mt = 0; mt < 2; ++mt)
                    at[mt][nt] = __builtin_amdgcn_mfma_f32_16x16x32_bf16(
                        wtf[mt], sb[nt], at[mt][nt], 0, 0, 0);
        }
#pragma unroll
        for (int mt = 0; mt < 2; ++mt)
#pragma unroll
            for (int nt = 0; nt < 4; ++nt) {
                const long es = (long)tile * TE + nt * 16 + ln;
                short4v p;
#pragma unroll
                for (int r = 0; r < 4; ++r)
                    p[r] = f2b((a3[mt][nt][r] + biv[mt][r]) * at[mt][nt][r]);
                *(short4v*)(msg_q + es * Hdim + mch0 + mt * 16 + q * 4) = p;
            }
        __syncthreads();
    }
}

// ---------------- node gather kernel (sorted path) ----------------
// Per 64-node tile: gather contiguous msg rows -> f32 reg accumulate ->
// h_new = h + agg_s @ W_up + b_up ; gate = sigmoid(h_new @ W_gate + b_gate) ;
// h_eq_new = h_eq + agg_q * gate
__global__ __launch_bounds__(256, 2)
void ei_node_gather(const void* __restrict__ hmat,
                    const void* __restrict__ heq,
                    const void* __restrict__ Wup,
                    const void* __restrict__ bup,
                    const void* __restrict__ Wg,
                    const void* __restrict__ bg,
                    const int*  __restrict__ rs,
                    const short* __restrict__ msg_s,
                    const short* __restrict__ msg_q,
                    void* __restrict__ outp,
                    const int* __restrict__ flags,
                    int N)
{
    __shared__ alignas(16) short Xa[TE][YLD];
    __shared__ alignas(16) short Yh[TE][YLD];
    __shared__ alignas(16) float Qa[TE][QLD];

    const int dtf = flags[0];

    const int tid  = threadIdx.x;
    const int lane = tid & 63;
    const int wv   = tid >> 6;
    const int q    = lane >> 4;
    const int ln   = lane & 15;
    const int mch0 = wv * 32;

    short* outh_b = (short*)outp;
    short* outq_b = outh_b + (long)N * Hdim;
    float* outh_f = (float*)outp;
    float* outq_f = outh_f + (long)N * Hdim;

    short8 wuf[4][2], wgf[4][2];
    float4v buv[2], bgv[2];
#pragma unroll
    for (int mt = 0; mt < 2; ++mt) {
        const int m = mch0 + mt * 16 + ln;
#pragma unroll
        for (int kc = 0; kc < 4; ++kc) {
            short8 t, u;
            const int k0 = kc * 32 + q * 8;
#pragma unroll
            for (int j = 0; j < 8; ++j) {
                const long idx = (long)(k0 + j) * Hdim + m;
                t[j] = dtf ? ((const short*)Wup)[idx] : f2b(((const float*)Wup)[idx]);
                u[j] = dtf ? ((const short*)Wg)[idx]  : f2b(((const float*)Wg)[idx]);
            }
            wuf[kc][mt] = t;
            wgf[kc][mt] = u;
        }
        const int cb = mch0 + mt * 16 + q * 4;
#pragma unroll
        for (int r = 0; r < 4; ++r) {
            buv[mt][r] = ldf(bup, cb + r, dtf);
            bgv[mt][r] = ldf(bg, cb + r, dtf);
        }
    }

    const int e_loc = tid >> 2;
    const int part  = tid & 3;
    const int nb    = blockIdx.x * TE;
    const int node  = nb + e_loc;

    // ---- gather-reduce this node's contiguous message rows ----
    float accs[32], accq[32];
#pragma unroll
    for (int i = 0; i < 32; ++i) { accs[i] = 0.f; accq[i] = 0.f; }
    if (node < N) {
        const int r0 = rs[node], r1 = rs[node + 1];
        for (int r = r0; r < r1; ++r) {
            const long rowb = (long)r * Hdim + part * 32;
            const short8* ps = (const short8*)(msg_s + rowb);
            const short8* pq = (const short8*)(msg_q + rowb);
#pragma unroll
            for (int c = 0; c < 4; ++c) {
                const short8 vs = ps[c];
                const short8 vq = pq[c];
#pragma unroll
                for (int k = 0; k < 8; ++k) {
                    accs[c * 8 + k] += b2f(vs[k]);
                    accq[c * 8 + k] += b2f(vq[k]);
                }
            }
        }
    }
    // stage bf16(agg_s) into Xa, f32 agg_q into Qa
#pragma unroll
    for (int c = 0; c < 4; ++c) {
        short8 t;
#pragma unroll
        for (int k = 0; k < 8; ++k) t[k] = f2b(accs[c * 8 + k]);
        *(short8*)&Xa[e_loc][part * 32 + c * 8] = t;
    }
#pragma unroll
    for (int c = 0; c < 8; ++c) {
        float4v v;
#pragma unroll
        for (int k = 0; k < 4; ++k) v[k] = accq[c * 4 + k];
        *(float4v*)&Qa[e_loc][part * 32 + c * 4] = v;
    }
    __syncthreads();

    // ---- GEMM: agg_s @ W_up ; h_new epilogue ----
    float4v au[2][4] = {};
#pragma unroll
    for (int kc = 0; kc < 4; ++kc) {
        short8 ab[4];
#pragma unroll
        for (int nt = 0; nt < 4; ++nt)
            ab[nt] = *(const short8*)&Xa[nt * 16 + ln][kc * 32 + q * 8];
#pragma unroll
        for (int nt = 0; nt < 4; ++nt)
#pragma unroll
            for (int mt = 0; mt < 2; ++mt)
                au[mt][nt] = __builtin_amdgcn_mfma_f32_16x16x32_bf16(
                    wuf[kc][mt], ab[nt], au[mt][nt], 0, 0, 0);
    }
#pragma unroll
    for (int mt = 0; mt < 2; ++mt)
#pragma unroll
        for (int nt = 0; nt < 4; ++nt) {
            const int nd = nb + nt * 16 + ln;
            const int ch = mch0 + mt * 16 + q * 4;
            short4v p;
            if (nd < N) {
                float hv[4];
                if (dtf) {
                    const short4v x = *(const short4v*)((const short*)hmat + (long)nd * Hdim + ch);
#pragma unroll
                    for (int r = 0; r < 4; ++r) hv[r] = b2f(x[r]);
                } else {
                    const float4v x = *(const float4v*)((const float*)hmat + (long)nd * Hdim + ch);
#pragma unroll
                    for (int r = 0; r < 4; ++r) hv[r] = x[r];
                }
                float4v o;
#pragma unroll
                for (int r = 0; r < 4; ++r) {
                    o[r] = hv[r] + au[mt][nt][r] + buv[mt][r];
                    p[r] = f2b(o[r]);
                }
                if (dtf) *(short4v*)(outh_b + (long)nd * Hdim + ch) = p;
                else     *(float4v*)(outh_f + (long)nd * Hdim + ch) = o;
            } else {
#pragma unroll
                for (int r = 0; r < 4; ++r) p[r] = 0;
            }
            *(short4v*)&Yh[nt * 16 + ln][ch] = p;
        }
    __syncthreads();

    // ---- GEMM: h_new @ W_gate ; h_eq_new epilogue ----
    float4v ag[2][4] = {};
#pragma unroll
    for (int kc = 0; kc < 4; ++kc) {
        short8 yb[4];
#pragma unroll
        for (int nt = 0; nt < 4; ++nt)
            yb[nt] = *(const short8*)&Yh[nt * 16 + ln][kc * 32 + q * 8];
#pragma unroll
        for (int nt = 0; nt < 4; ++nt)
#pragma unroll
            for (int mt = 0; mt < 2; ++mt)
                ag[mt][nt] = __builtin_amdgcn_mfma_f32_16x16x32_bf16(
                    wgf[kc][mt], yb[nt], ag[mt][nt], 0, 0, 0);
    }
#pragma unroll
    for (int mt = 0; mt < 2; ++mt)
#pragma unroll
        for (int nt = 0; nt < 4; ++nt) {
            const int nd = nb + nt * 16 + ln;
            if (nd >= N) continue;
            const int ch = mch0 + mt * 16 + q * 4;
            const float4v aq = *(const float4v*)&Qa[nt * 16 + ln][ch];
            float hev[4];
            if (dtf) {
                const short4v x = *(const short4v*)((const short*)heq + (long)nd * Hdim + ch);
#pragma unroll
                for (int r = 0; r < 4; ++r) hev[r] = b2f(x[r]);
            } else {
                const float4v x = *(const float4v*)((const float*)heq + (long)nd * Hdim + ch);
#pragma unroll
                for (int r = 0; r < 4; ++r) hev[r] = x[r];
            }
            short4v p;
            float4v o;
#pragma unroll
            for (int r = 0; r < 4; ++r) {
                const float g = 1.f / (1.f + __expf(-(ag[mt][nt][r] + bgv[mt][r])));
                o[r] = hev[r] + aq[r] * g;
                p[r] = f2b(o[r]);
            }
            if (dtf) *(short4v*)(outq_b + (long)nd * Hdim + ch) = p;
            else     *(float4v*)(outq_f + (long)nd * Hdim + ch) = o;
        }
}

// ================= R2 fallback path (atomic scatter-add) =================

__global__ __launch_bounds__(256, 2)
void ei_edge_kernel(const void* __restrict__ hmat,
                    const void* __restrict__ efeat,
                    const void* __restrict__ shmat,
                    const void* __restrict__ edge_i,
                    const void* __restrict__ edge_j,
                    const void* __restrict__ W1,
                    const void* __restrict__ b1,
                    const void* __restrict__ W2,
                    const void* __restrict__ b2,
                    const void* __restrict__ Win,
                    const void* __restrict__ bin,
                    const void* __restrict__ Wtp,
                    float* __restrict__ agg_s,
                    float* __restrict__ agg_q,
                    const int* __restrict__ flags,
                    int ntiles)
{
    __shared__ alignas(16) short Xs[TE][XLD];
    __shared__ alignas(16) short Ys[TE][YLD];
    __shared__ alignas(16) short Ss[TE][SLD];
    __shared__ int ids[TE];

    const int dtf = flags[0];
    const int dti = flags[1];

    const int tid  = threadIdx.x;
    const int lane = tid & 63;
    const int wv   = tid >> 6;
    const int q    = lane >> 4;
    const int ln   = lane & 15;
    const int mch0 = wv * 32;

    for (int i = tid; i < TE * XLD; i += 256) ((short*)Xs)[i] = 0;
    for (int i = tid; i < TE * YLD; i += 256) ((short*)Ys)[i] = 0;
    for (int i = tid; i < TE * SLD; i += 256) ((short*)Ss)[i] = 0;
    __syncthreads();

    short8 w1f[6][2], w2f[4][2], wif[4][2], wtf[2];
    float4v b1v[2], b2v[2], biv[2];
#pragma unroll
    for (int mt = 0; mt < 2; ++mt) {
        const int m = mch0 + mt * 16 + ln;
#pragma unroll
        for (int kc = 0; kc < 6; ++kc) {
            short8 t;
            const int k0 = kc * 32 + q * 8;
#pragma unroll
            for (int j = 0; j < 8; ++j) t[j] = dtf ? ((const short*)W1)[(long)(k0 + j) * Hdim + m]
                                                   : f2b(((const float*)W1)[(long)(k0 + j) * Hdim + m]);
            w1f[kc][mt] = t;
        }
#pragma unroll
        for (int kc = 0; kc < 4; ++kc) {
            short8 t, u;
            const int k0 = kc * 32 + q * 8;
#pragma unroll
            for (int j = 0; j < 8; ++j) {
                const long idx = (long)(k0 + j) * Hdim + m;
                t[j] = dtf ? ((const short*)W2)[idx]  : f2b(((const float*)W2)[idx]);
                u[j] = dtf ? ((const short*)Win)[idx] : f2b(((const float*)Win)[idx]);
            }
            w2f[kc][mt] = t;
            wif[kc][mt] = u;
        }
        {
            short8 t;
#pragma unroll
            for (int j = 0; j < 8; ++j) {
                const int k = q * 8 + j;
                t[j] = (k < Mdim) ? (dtf ? ((const short*)Wtp)[(long)k * Hdim + m]
                                         : f2b(((const float*)Wtp)[(long)k * Hdim + m]))
                                  : (short)0;
            }
            wtf[mt] = t;
        }
        const int cb = mch0 + mt * 16 + q * 4;
#pragma unroll
        for (int r = 0; r < 4; ++r) {
            b1v[mt][r] = ldf(b1, cb + r, dtf);
            b2v[mt][r] = ldf(b2, cb + r, dtf);
            biv[mt][r] = ldf(bin, cb + r, dtf);
        }
    }

    const int e_loc = tid >> 2;
    const int part  = tid & 3;

    for (int tile = blockIdx.x; tile < ntiles; tile += gridDim.x) {
        {
            const int edge = tile * TE + e_loc;
            const int j = ldi(edge_j, edge, dti);
            if (dtf) {
                const uint4* hsrc = (const uint4*)((const short*)hmat + (long)j * Hdim);
                uint4* xd = (uint4*)&Xs[e_loc][part * 32];
#pragma unroll
                for (int i = 0; i < 4; ++i) xd[i] = hsrc[part * 4 + i];
                const uint4* fsrc = (const uint4*)((const short*)efeat + (long)edge * Fdim);
                uint4* fd = (uint4*)&Xs[e_loc][Hdim + part * 16];
                fd[0] = fsrc[part * 2 + 0];
                fd[1] = fsrc[part * 2 + 1];
                if (part == 0) {
                    const uint4* ssrc = (const uint4*)((const short*)shmat + (long)edge * Mdim);
                    ((uint4*)&Ss[e_loc][0])[0] = ssrc[0];
                    ((uint4*)&Ss[e_loc][0])[1] = ssrc[1];
                }
            } else {
                const float4v* hs = (const float4v*)((const float*)hmat + (long)j * Hdim + part * 32);
#pragma unroll
                for (int c = 0; c < 4; ++c) {
                    const float4v v0 = hs[2 * c], v1 = hs[2 * c + 1];
                    short8 t;
#pragma unroll
                    for (int r = 0; r < 4; ++r) { t[r] = f2b(v0[r]); t[4 + r] = f2b(v1[r]); }
                    *(short8*)&Xs[e_loc][part * 32 + c * 8] = t;
                }
                const float4v* fs = (const float4v*)((const float*)efeat + (long)edge * Fdim + part * 16);
#pragma unroll
                for (int c = 0; c < 2; ++c) {
                    const float4v v0 = fs[2 * c], v1 = fs[2 * c + 1];
                    short8 t;
#pragma unroll
                    for (int r = 0; r < 4; ++r) { t[r] = f2b(v0[r]); t[4 + r] = f2b(v1[r]); }
                    *(short8*)&Xs[e_loc][Hdim + part * 16 + c * 8] = t;
                }
                if (part == 0) {
                    const float4v* ss = (const float4v*)((const float*)shmat + (long)edge * Mdim);
#pragma unroll
                    for (int c = 0; c < 2; ++c) {
                        const float4v v0 = ss[2 * c], v1 = ss[2 * c + 1];
                        short8 t;
#pragma unroll
                        for (int r = 0; r < 4; ++r) { t[r] = f2b(v0[r]); t[4 + r] = f2b(v1[r]); }
                        *(short8*)&Ss[e_loc][c * 8] = t;
                    }
                }
            }
            if (tid < TE) ids[tid] = ldi(edge_i, tile * TE + tid, dti);
        }
        __syncthreads();

        float4v a1[2][4] = {};
#pragma unroll
        for (int kc = 0; kc < 6; ++kc) {
            short8 xb[4];
#pragma unroll
            for (int nt = 0; nt < 4; ++nt)
                xb[nt] = *(const short8*)&Xs[nt * 16 + ln][kc * 32 + q * 8];
#pragma unroll
            for (int nt = 0; nt < 4; ++nt)
#pragma unroll
                for (int mt = 0; mt < 2; ++mt)
                    a1[mt][nt] = __builtin_amdgcn_mfma_f32_16x16x32_bf16(
                        w1f[kc][mt], xb[nt], a1[mt][nt], 0, 0, 0);
        }
#pragma unroll
        for (int mt = 0; mt < 2; ++mt)
#pragma unroll
            for (int nt = 0; nt < 4; ++nt) {
                short4v p;
#pragma unroll
                for (int r = 0; r < 4; ++r) {
                    const float y = a1[mt][nt][r] + b1v[mt][r];
                    const float s = y / (1.f + __expf(-y));
                    p[r] = f2b(s);
                }
                *(short4v*)&Ys[nt * 16 + ln][mch0 + mt * 16 + q * 4] = p;
            }
        __syncthreads();

        float4v a2[2][4] = {};
#pragma unroll
        for (int kc = 0; kc < 4; ++kc) {
            short8 yb[4];
#pragma unroll
            for (int nt = 0; nt < 4; ++nt)
                yb[nt] = *(const short8*)&Ys[nt * 16 + ln][kc * 32 + q * 8];
#pragma unroll
            for (int nt = 0; nt < 4; ++nt)
#pragma unroll
                for (int mt = 0; mt < 2; ++mt)
                    a2[mt][nt] = __builtin_amdgcn_mfma_f32_16x16x32_bf16(
                        w2f[kc][mt], yb[nt], a2[mt][nt], 0, 0, 0);
        }
#pragma unroll
        for (int mt = 0; mt < 2; ++mt)
#pragma unroll
            for (int nt = 0; nt < 4; ++nt) {
                const int nd = ids[nt * 16 + ln];
                float* dst = agg_s + (long)nd * Hdim + mch0 + mt * 16 + q * 4;
#pragma unroll
                for (int r = 0; r < 4; ++r)
                    unsafeAtomicAdd(dst + r, a2[mt][nt][r] + b2v[mt][r]);
            }

        float4v a3[2][4] = {};
        float4v at[2][4] = {};
#pragma unroll
        for (int kc = 0; kc < 4; ++kc) {
            short8 xb[4];
#pragma unroll
            for (int nt = 0; nt < 4; ++nt)
                xb[nt] = *(const short8*)&Xs[nt * 16 + ln][kc * 32 + q * 8];
#pragma unroll
            for (int nt = 0; nt < 4; ++nt)
#pragma unroll
                for (int mt = 0; mt < 2; ++mt)
                    a3[mt][nt] = __builtin_amdgcn_mfma_f32_16x16x32_bf16(
                        wif[kc][mt], xb[nt], a3[mt][nt], 0, 0, 0);
        }
        {
            short8 sb[4];
#pragma unroll
            for (int nt = 0; nt < 4; ++nt)
                sb[nt] = *(const short8*)&Ss[nt * 16 + ln][q * 8];
#pragma unroll
            for (int nt = 0; nt < 4; ++nt)
#pragma unroll
                for (int mt = 0; mt < 2; ++mt)
                    at[mt][nt] = __builtin_amdgcn_mfma_f32_16x16x32_bf16(
                        wtf[mt], sb[nt], at[mt][nt], 0, 0, 0);
        }
#pragma unroll
        for (int mt = 0; mt < 2; ++mt)
#pragma unroll
            for (int nt = 0; nt < 4; ++nt) {
                const int nd = ids[nt * 16 + ln];
                float* dst = agg_q + (long)nd * Hdim + mch0 + mt * 16 + q * 4;
#pragma unroll
                for (int r = 0; r < 4; ++r)
                    unsafeAtomicAdd(dst + r,
                        (a3[mt][nt][r] + biv[mt][r]) * at[mt][nt][r]);
            }
        __syncthreads();
    }
}

__global__ __launch_bounds__(256, 2)
void ei_node_kernel(const void* __restrict__ hmat,
                    const void* __restrict__ heq,
                    const void* __restrict__ Wup,
                    const void* __restrict__ bup,
                    const void* __restrict__ Wg,
                    const void* __restrict__ bg,
                    const float* __restrict__ agg_s,
                    const float* __restrict__ agg_q,
                    void* __restrict__ outp,
                    const int* __restrict__ flags,
                    int N)
{
    __shared__ alignas(16) short Xa[TE][YLD];
    __shared__ alignas(16) short Yh[TE][YLD];

    const int dtf = flags[0];

    const int tid  = threadIdx.x;
    const int lane = tid & 63;
    const int wv   = tid >> 6;
    const int q    = lane >> 4;
    const int ln   = lane & 15;
    const int mch0 = wv * 32;

    short* outh_b = (short*)outp;
    short* outq_b = outh_b + (long)N * Hdim;
    float* outh_f = (float*)outp;
    float* outq_f = outh_f + (long)N * Hdim;

    short8 wuf[4][2], wgf[4][2];
    float4v buv[2], bgv[2];
#pragma unroll
    for (int mt = 0; mt < 2; ++mt) {
        const int m = mch0 + mt * 16 + ln;
#pragma unroll
        for (int kc = 0; kc < 4; ++kc) {
            short8 t, u;
            const int k0 = kc * 32 + q * 8;
#pragma unroll
            for (int j = 0; j < 8; ++j) {
                const long idx = (long)(k0 + j) * Hdim + m;
                t[j] = dtf ? ((const short*)Wup)[idx] : f2b(((const float*)Wup)[idx]);
                u[j] = dtf ? ((const short*)Wg)[idx]  : f2b(((const float*)Wg)[idx]);
            }
            wuf[kc][mt] = t;
            wgf[kc][mt] = u;
        }
        const int cb = mch0 + mt * 16 + q * 4;
#pragma unroll
        for (int r = 0; r < 4; ++r) {
            buv[mt][r] = ldf(bup, cb + r, dtf);
            bgv[mt][r] = ldf(bg, cb + r, dtf);
        }
    }

    const int e_loc = tid >> 2;
    const int part  = tid & 3;
    const int nb    = blockIdx.x * TE;

    {
        const int node = nb + e_loc;
        if (node < N) {
            const float4v* src = (const float4v*)(agg_s + (long)node * Hdim + part * 32);
#pragma unroll
            for (int c = 0; c < 4; ++c) {
                const float4v v0 = src[2 * c], v1 = src[2 * c + 1];
                short8 t;
#pragma unroll
                for (int r = 0; r < 4; ++r) { t[r] = f2b(v0[r]); t[4 + r] = f2b(v1[r]); }
                *(short8*)&Xa[e_loc][part * 32 + c * 8] = t;
            }
        } else {
            short8 z = {};
#pragma unroll
            for (int c = 0; c < 4; ++c)
                *(short8*)&Xa[e_loc][part * 32 + c * 8] = z;
        }
    }
    __syncthreads();

    float4v au[2][4] = {};
#pragma unroll
    for (int kc = 0; kc < 4; ++kc) {
        short8 ab[4];
#pragma unroll
        for (int nt = 0; nt < 4; ++nt)
            ab[nt] = *(const short8*)&Xa[nt * 16 + ln][kc * 32 + q * 8];
#pragma unroll
        for (int nt = 0; nt < 4; ++nt)
#pragma unroll
            for (int mt = 0; mt < 2; ++mt)
                au[mt][nt] = __builtin_amdgcn_mfma_f32_16x16x32_bf16(
                    wuf[kc][mt], ab[nt], au[mt][nt], 0, 0, 0);
    }
#pragma unroll
    for (int mt = 0; mt < 2; ++mt)
#pragma unroll
        for (int nt = 0; nt < 4; ++nt) {
            const int node = nb + nt * 16 + ln;
            const int ch = mch0 + mt * 16 + q * 4;
            short4v p;
            if (node < N) {
                float hv[4];
                if (dtf) {
                    const short4v x = *(const short4v*)((const short*)hmat + (long)node * Hdim + ch);
#pragma unroll
                    for (int r = 0; r < 4; ++r) hv[r] = b2f(x[r]);
                } else {
                    const float4v x = *(const float4v*)((const float*)hmat + (long)node * Hdim + ch);
#pragma unroll
                    for (int r = 0; r < 4; ++r) hv[r] = x[r];
                }
                float4v o;
#pragma unroll
                for (int r = 0; r < 4; ++r) {
                    o[r] = hv[r] + au[mt][nt][r] + buv[mt][r];
                    p[r] = f2b(o[r]);
                }
                if (dtf) *(short4v*)(outh_b + (long)node * Hdim + ch) = p;
                else     *(float4v*)(outh_f + (long)node * Hdim + ch) = o;
            } else {
#pragma unroll
                for (int r = 0; r < 4; ++r) p[r] = 0;
            }
            *(short4v*)&Yh[nt * 16 + ln][ch] = p;
        }
    __syncthreads();

    float4v ag[2][4] = {};
#pragma unroll
    for (int kc = 0; kc < 4; ++kc) {
        short8 yb[4];
#pragma unroll
        for (int nt = 0; nt < 4; ++nt)
            yb[nt] = *(const short8*)&Yh[nt * 16 + ln][kc * 32 + q * 8];
#pragma unroll
        for (int nt = 0; nt < 4; ++nt)
#pragma unroll
            for (int mt = 0; mt < 2; ++mt)
                ag[mt][nt] = __builtin_amdgcn_mfma_f32_16x16x32_bf16(
                    wgf[kc][mt], yb[nt], ag[mt][nt], 0, 0, 0);
    }
#pragma unroll
    for (int mt = 0; mt < 2; ++mt)
#pragma unroll
        for (int nt = 0; nt < 4; ++nt) {
            const int node = nb + nt * 16 + ln;
            if (node >= N) continue;
            const int ch = mch0 + mt * 16 + q * 4;
            const float4v aq = *(const float4v*)(agg_q + (long)node * Hdim + ch);
            float hev[4];
            if (dtf) {
                const short4v x = *(const short4v*)((const short*)heq + (long)node * Hdim + ch);
#pragma unroll
                for (int r = 0; r < 4; ++r) hev[r] = b2f(x[r]);
            } else {
                const float4v x = *(const float4v*)((const float*)heq + (long)node * Hdim + ch);
#pragma unroll
                for (int r = 0; r < 4; ++r) hev[r] = x[r];
            }
            short4v p;
            float4v o;
#pragma unroll
            for (int r = 0; r < 4; ++r) {
                const float g = 1.f / (1.f + __expf(-(ag[mt][nt][r] + bgv[mt][r])));
                o[r] = hev[r] + aq[r] * g;
                p[r] = f2b(o[r]);
            }
            if (dtf) *(short4v*)(outq_b + (long)node * Hdim + ch) = p;
            else     *(float4v*)(outq_f + (long)node * Hdim + ch) = o;
        }
}

extern "C" void kernel_launch(void* const* d_in, const int* in_sizes, int n_in,
                              void* d_out, int out_size, void* d_ws, size_t ws_size,
                              hipStream_t stream)
{
    (void)n_in; (void)out_size;
    const void* hmat  = d_in[0];
    const void* heq   = d_in[1];
    const void* efeat = d_in[2];
    const void* shm   = d_in[3];
    const void* ei    = d_in[4];
    const void* ej    = d_in[5];
    const void* Win   = d_in[6];
    const void* bin   = d_in[7];
    const void* Wg    = d_in[8];
    const void* bg    = d_in[9];
    const void* W1    = d_in[10];
    const void* b1    = d_in[11];
    const void* W2    = d_in[12];
    const void* b2    = d_in[13];
    const void* Wup   = d_in[14];
    const void* bup   = d_in[15];
    const void* Wtp   = d_in[16];

    const int N = in_sizes[0] / Hdim;
    const int E = in_sizes[2] / Fdim;

    // sorted-path ws layout
    auto al = [](size_t x) { return (x + 255) & ~(size_t)255; };
    size_t off = 8;                                   // flags
    off = al(off); const size_t rs_off   = off; off += (size_t)(N + 1) * 4;
    off = al(off); const size_t cur_off  = off; off += (size_t)N * 4;
    off = al(off); const size_t perm_off = off; off += (size_t)E * 4;
    off = al(off); const size_t ms_off   = off; off += (size_t)E * Hdim * 2;
    off = al(off); const size_t mq_off   = off; off += (size_t)E * Hdim * 2;
    const size_t need = off;

    char* w = (char*)d_ws;

    if (ws_size >= need) {
        int*   flags = (int*)w;
        int*   rs    = (int*)(w + rs_off);
        int*   cur   = (int*)(w + cur_off);
        int*   perm  = (int*)(w + perm_off);
        short* ms    = (short*)(w + ms_off);
        short* mq    = (short*)(w + mq_off);

        ei_sniff_kernel<<<1, 64, 0, stream>>>((const unsigned*)hmat, (const unsigned*)ei, flags);
        hipMemsetAsync(cur, 0, (size_t)N * 4, stream);
        ei_hist_kernel<<<256, 256, 0, stream>>>(ei, cur, flags, E);
        ei_scan_kernel<<<1, 1024, 0, stream>>>(cur, rs, N, E);
        ei_scatter_kernel<<<256, 256, 0, stream>>>(ei, cur, perm, flags, E);
        ei_edge_sorted<<<1024, 256, 0, stream>>>(hmat, efeat, shm, ej, perm,
                                                 W1, b1, W2, b2, Win, bin, Wtp,
                                                 ms, mq, flags, E / TE);
        ei_node_gather<<<(N + TE - 1) / TE, 256, 0, stream>>>(
            hmat, heq, Wup, bup, Wg, bg, rs, ms, mq, d_out, flags, N);
    } else {
        // fallback: R2 atomic path (known-passing)
        float* agg_s = (float*)d_ws;
        float* agg_q = agg_s + (long)N * Hdim;
        int* flags = (int*)(w + (size_t)2 * N * Hdim * sizeof(float));

        ei_sniff_kernel<<<1, 64, 0, stream>>>((const unsigned*)hmat, (const unsigned*)ei, flags);
        hipMemsetAsync(d_ws, 0, (size_t)2 * N * Hdim * sizeof(float), stream);
        ei_edge_kernel<<<1024, 256, 0, stream>>>(hmat, efeat, shm, ei, ej,
                                                 W1, b1, W2, b2, Win, bin, Wtp,
                                                 agg_s, agg_q, flags, E / TE);
        ei_node_kernel<<<(N + TE - 1) / TE, 256, 0, stream>>>(
            hmat, heq, Wup, bup, Wg, bg, agg_s, agg_q, d_out, flags, N);
    }
}

// Round 4
// 1178.570 us; speedup vs baseline: 3.2088x; 1.1474x over previous
//
#include <hip/hip_runtime.h>
#include <hip/hip_bf16.h>

// EquivariantInteractionBlock on MI355X (gfx950).
// R4: kill the 512MB msg round-trip.
//  - Fold: segsum(silu(.)@W2+b2)@Wup = segsum(Y)@(W2*Wup) + deg*(b2@Wup).
//  - Sorted edges -> in-tile segmented reduction in LDS; interior runs = plain
//    coalesced stores (exclusive writer), boundary runs = f32 atomics (~8e6).
//  - ws: 517MB -> 56MB. Dual-dtype sniff kept (bf16/f32 floats, i32/i64 idx).

#define Hdim 128
#define Fdim 64
#define Mdim 16
#define TE   64    // edges (or nodes) per block tile
#define XLD  200   // LDS leading dim for [64][192] tile (16B-aligned rows)
#define YLD  132   // LDS leading dim for [64][128] tiles (8B-aligned rows)
#define SLD  40    // LDS leading dim for sh [64][32] tile

typedef __attribute__((ext_vector_type(8))) short short8;
typedef __attribute__((ext_vector_type(4))) short short4v;
typedef __attribute__((ext_vector_type(4))) float float4v;

__device__ __forceinline__ float b2f(short s) {
    union { unsigned u; float f; } c;
    c.u = ((unsigned)(unsigned short)s) << 16;
    return c.f;
}
__device__ __forceinline__ short f2b(float f) {
    union { __hip_bfloat16 h; short s; } c;
    c.h = __float2bfloat16(f);
    return c.s;
}
__device__ __forceinline__ float ldf(const void* p, long i, int isbf) {
    return isbf ? b2f(((const short*)p)[i]) : ((const float*)p)[i];
}
__device__ __forceinline__ int ldi(const void* p, long i, int is64) {
    return is64 ? (int)((const long long*)p)[i] : ((const int*)p)[i];
}

// flags[0] = 1 if float tensors are bf16, 0 if f32
// flags[1] = 1 if index tensors are int64, 0 if int32
__global__ void ei_sniff_kernel(const unsigned* __restrict__ hw,
                                const unsigned* __restrict__ iw,
                                int* __restrict__ flags)
{
    __shared__ int cf[64], ci[64];
    const int t = threadIdx.x;
    int c1 = 0, c2 = 0;
#pragma unroll
    for (int k = 0; k < 4; ++k) {
        const unsigned w = hw[t + 64 * k];
        const unsigned e = (w >> 7) & 0xFFu;
        c1 += (e >= 100u && e <= 140u) ? 1 : 0;
        const unsigned wi = iw[2 * (t + 64 * k) + 1];
        c2 += (wi == 0u) ? 1 : 0;
    }
    cf[t] = c1; ci[t] = c2;
    __syncthreads();
    if (t == 0) {
        int s1 = 0, s2 = 0;
        for (int i = 0; i < 64; ++i) { s1 += cf[i]; s2 += ci[i]; }
        flags[0] = (s1 >= 192) ? 1 : 0;
        flags[1] = (s2 >= 200) ? 1 : 0;
    }
}

// ---------------- sort path: hist -> scan -> scatter ----------------

__global__ void ei_hist_kernel(const void* __restrict__ edge_i,
                               int* __restrict__ hist,
                               const int* __restrict__ flags, int E_)
{
    const int dti = flags[1];
    int i = blockIdx.x * blockDim.x + threadIdx.x;
    const int stride = gridDim.x * blockDim.x;
    for (; i < E_; i += stride) atomicAdd(&hist[ldi(edge_i, i, dti)], 1);
}

// 1 block, 1024 threads. hist doubles as cursor output (row starts).
__global__ void ei_scan_kernel(int* __restrict__ hist,
                               int* __restrict__ rs, int N_, int E_)
{
    __shared__ int buf[1024];
    const int t = threadIdx.x;
    const int chunk = (N_ + 1023) >> 10;
    const int base = t * chunk;
    int s = 0;
    for (int i = 0; i < chunk; ++i) {
        const int idx = base + i;
        if (idx < N_) s += hist[idx];
    }
    buf[t] = s;
    __syncthreads();
    for (int d = 1; d < 1024; d <<= 1) {
        const int v = (t >= d) ? buf[t - d] : 0;
        __syncthreads();
        buf[t] += v;
        __syncthreads();
    }
    int run = buf[t] - s;   // exclusive prefix
    for (int i = 0; i < chunk; ++i) {
        const int idx = base + i;
        if (idx >= N_) break;
        const int h = hist[idx];
        rs[idx] = run;
        hist[idx] = run;    // becomes scatter cursor
        run += h;
    }
    if (t == 0) rs[N_] = E_;
}

__global__ void ei_scatter_kernel(const void* __restrict__ edge_i,
                                  int* __restrict__ cur,
                                  int* __restrict__ perm,
                                  const int* __restrict__ flags, int E_)
{
    const int dti = flags[1];
    int i = blockIdx.x * blockDim.x + threadIdx.x;
    const int stride = gridDim.x * blockDim.x;
    for (; i < E_; i += stride) {
        const int c = ldi(edge_i, i, dti);
        const int p = atomicAdd(&cur[c], 1);
        perm[p] = i;
    }
}

// ---------------- W2up = W2 @ W_up (bf16), bu2 = b2 @ W_up (f32) ------------
__global__ void ei_w2up_kernel(const void* __restrict__ W2,
                               const void* __restrict__ Wup,
                               const void* __restrict__ b2,
                               short* __restrict__ w2up,
                               float* __restrict__ bu2,
                               const int* __restrict__ flags)
{
    const int dtf = flags[0];
    const int o = threadIdx.x;   // 0..127
    const int i = blockIdx.x;    // 0..128 (128 = bias row)
    float acc = 0.f;
    for (int m = 0; m < Hdim; ++m) {
        const float a = (i < Hdim) ? ldf(W2, (long)i * Hdim + m, dtf)
                                   : ldf(b2, m, dtf);
        acc += a * ldf(Wup, (long)m * Hdim + o, dtf);
    }
    if (i < Hdim) w2up[i * Hdim + o] = f2b(acc);
    else          bu2[o] = acc;
}

// ---------------- sorted edge kernel with in-tile segmented reduce ----------
//   Y  = silu([h_j|edge_feat] @ W1 + b1)                 -> segsum -> agg_y
//   eq = (h_j @ W_in + b_in) * (sh @ W_tp)               -> segsum -> agg_q
__global__ __launch_bounds__(256, 2)
void ei_edge_sorted(const void* __restrict__ hmat,
                    const void* __restrict__ efeat,
                    const void* __restrict__ shmat,
                    const void* __restrict__ edge_j,
                    const int*  __restrict__ perm,
                    const int*  __restrict__ edge_i_sorted_src, // raw edge_i
                    const void* __restrict__ W1,
                    const void* __restrict__ b1,
                    const void* __restrict__ Win,
                    const void* __restrict__ bin,
                    const void* __restrict__ Wtp,
                    float* __restrict__ agg_y,
                    float* __restrict__ agg_q,
                    const int* __restrict__ flags,
                    int ntiles)
{
    __shared__ alignas(16) short Xs[TE][XLD];  // [edge][k] ([h_j | edge_feat])
    __shared__ alignas(16) short Ys[TE][YLD];  // silu output (bf16)
    __shared__ alignas(16) short Qs[TE][YLD];  // eq msg (bf16)
    __shared__ alignas(16) short Ss[TE][SLD];  // sh [0..15], zeros [16..31]
    __shared__ int ids[TE];                    // sorted destination ids

    const int dtf = flags[0];
    const int dti = flags[1];

    const int tid  = threadIdx.x;
    const int lane = tid & 63;
    const int wv   = tid >> 6;
    const int q    = lane >> 4;
    const int ln   = lane & 15;
    const int mch0 = wv * 32;

    // one-time zero (covers pads; Ss[16..31] must stay zero)
    for (int i = tid; i < TE * XLD; i += 256) ((short*)Xs)[i] = 0;
    for (int i = tid; i < TE * YLD; i += 256) ((short*)Ys)[i] = 0;
    for (int i = tid; i < TE * YLD; i += 256) ((short*)Qs)[i] = 0;
    for (int i = tid; i < TE * SLD; i += 256) ((short*)Ss)[i] = 0;
    __syncthreads();

    // persistent weight A-fragments (lane m = out-channel, k contiguous-8)
    short8 w1f[6][2], wif[4][2], wtf[2];
    float4v b1v[2], biv[2];
#pragma unroll
    for (int mt = 0; mt < 2; ++mt) {
        const int m = mch0 + mt * 16 + ln;
#pragma unroll
        for (int kc = 0; kc < 6; ++kc) {
            short8 t;
            const int k0 = kc * 32 + q * 8;
#pragma unroll
            for (int j = 0; j < 8; ++j) t[j] = dtf ? ((const short*)W1)[(long)(k0 + j) * Hdim + m]
                                                   : f2b(((const float*)W1)[(long)(k0 + j) * Hdim + m]);
            w1f[kc][mt] = t;
        }
#pragma unroll
        for (int kc = 0; kc < 4; ++kc) {
            short8 u;
            const int k0 = kc * 32 + q * 8;
#pragma unroll
            for (int j = 0; j < 8; ++j) {
                const long idx = (long)(k0 + j) * Hdim + m;
                u[j] = dtf ? ((const short*)Win)[idx] : f2b(((const float*)Win)[idx]);
            }
            wif[kc][mt] = u;
        }
        {
            short8 t;
#pragma unroll
            for (int j = 0; j < 8; ++j) {
                const int k = q * 8 + j;
                t[j] = (k < Mdim) ? (dtf ? ((const short*)Wtp)[(long)k * Hdim + m]
                                         : f2b(((const float*)Wtp)[(long)k * Hdim + m]))
                                  : (short)0;
            }
            wtf[mt] = t;
        }
        const int cb = mch0 + mt * 16 + q * 4;
#pragma unroll
        for (int r = 0; r < 4; ++r) {
            b1v[mt][r] = ldf(b1, cb + r, dtf);
            biv[mt][r] = ldf(bin, cb + r, dtf);
        }
    }

    const int e_loc = tid >> 2;
    const int part  = tid & 3;

    for (int tile = blockIdx.x; tile < ntiles; tile += gridDim.x) {
        // ---- stage (gather by perm) ----
        {
            const int es = tile * TE + e_loc;       // sorted slot; E % 64 == 0
            const int e  = perm[es];
            const int j  = ldi(edge_j, e, dti);
            if (dtf) {
                const uint4* hsrc = (const uint4*)((const short*)hmat + (long)j * Hdim);
                uint4* xd = (uint4*)&Xs[e_loc][part * 32];
#pragma unroll
                for (int i = 0; i < 4; ++i) xd[i] = hsrc[part * 4 + i];
                const uint4* fsrc = (const uint4*)((const short*)efeat + (long)e * Fdim);
                uint4* fd = (uint4*)&Xs[e_loc][Hdim + part * 16];
                fd[0] = fsrc[part * 2 + 0];
                fd[1] = fsrc[part * 2 + 1];
                if (part == 0) {
                    const uint4* ssrc = (const uint4*)((const short*)shmat + (long)e * Mdim);
                    ((uint4*)&Ss[e_loc][0])[0] = ssrc[0];
                    ((uint4*)&Ss[e_loc][0])[1] = ssrc[1];
                }
            } else {
                const float4v* hs = (const float4v*)((const float*)hmat + (long)j * Hdim + part * 32);
#pragma unroll
                for (int c = 0; c < 4; ++c) {
                    const float4v v0 = hs[2 * c], v1 = hs[2 * c + 1];
                    short8 t;
#pragma unroll
                    for (int r = 0; r < 4; ++r) { t[r] = f2b(v0[r]); t[4 + r] = f2b(v1[r]); }
                    *(short8*)&Xs[e_loc][part * 32 + c * 8] = t;
                }
                const float4v* fs = (const float4v*)((const float*)efeat + (long)e * Fdim + part * 16);
#pragma unroll
                for (int c = 0; c < 2; ++c) {
                    const float4v v0 = fs[2 * c], v1 = fs[2 * c + 1];
                    short8 t;
#pragma unroll
                    for (int r = 0; r < 4; ++r) { t[r] = f2b(v0[r]); t[4 + r] = f2b(v1[r]); }
                    *(short8*)&Xs[e_loc][Hdim + part * 16 + c * 8] = t;
                }
                if (part == 0) {
                    const float4v* ss = (const float4v*)((const float*)shmat + (long)e * Mdim);
#pragma unroll
                    for (int c = 0; c < 2; ++c) {
                        const float4v v0 = ss[2 * c], v1 = ss[2 * c + 1];
                        short8 t;
#pragma unroll
                        for (int r = 0; r < 4; ++r) { t[r] = f2b(v0[r]); t[4 + r] = f2b(v1[r]); }
                        *(short8*)&Ss[e_loc][c * 8] = t;
                    }
                }
            }
            // sorted destination ids: edge_i[perm[es]] — scan order
            if (tid < TE) {
                const int e2 = perm[tile * TE + tid];
                ids[tid] = ldi(edge_i_sorted_src, e2, dti);
            }
        }
        __syncthreads();

        // ---- GEMM1: Y = silu(X @ W1 + b1), K = 192 -> Ys ----
        float4v a1[2][4] = {};
#pragma unroll
        for (int kc = 0; kc < 6; ++kc) {
            short8 xb[4];
#pragma unroll
            for (int nt = 0; nt < 4; ++nt)
                xb[nt] = *(const short8*)&Xs[nt * 16 + ln][kc * 32 + q * 8];
#pragma unroll
            for (int nt = 0; nt < 4; ++nt)
#pragma unroll
                for (int mt = 0; mt < 2; ++mt)
                    a1[mt][nt] = __builtin_amdgcn_mfma_f32_16x16x32_bf16(
                        w1f[kc][mt], xb[nt], a1[mt][nt], 0, 0, 0);
        }
#pragma unroll
        for (int mt = 0; mt < 2; ++mt)
#pragma unroll
            for (int nt = 0; nt < 4; ++nt) {
                short4v p;
#pragma unroll
                for (int r = 0; r < 4; ++r) {
                    const float y = a1[mt][nt][r] + b1v[mt][r];
                    const float s = y / (1.f + __expf(-y));
                    p[r] = f2b(s);
                }
                *(short4v*)&Ys[nt * 16 + ln][mch0 + mt * 16 + q * 4] = p;
            }

        // ---- GEMM3: eq = (h_j @ W_in + b_in) * (sh @ W_tp) -> Qs ----
        float4v a3[2][4] = {};
        float4v at[2][4] = {};
#pragma unroll
        for (int kc = 0; kc < 4; ++kc) {
            short8 xb[4];
#pragma unroll
            for (int nt = 0; nt < 4; ++nt)
                xb[nt] = *(const short8*)&Xs[nt * 16 + ln][kc * 32 + q * 8];
#pragma unroll
            for (int nt = 0; nt < 4; ++nt)
#pragma unroll
                for (int mt = 0; mt < 2; ++mt)
                    a3[mt][nt] = __builtin_amdgcn_mfma_f32_16x16x32_bf16(
                        wif[kc][mt], xb[nt], a3[mt][nt], 0, 0, 0);
        }
        {
            short8 sb[4];
#pragma unroll
            for (int nt = 0; nt < 4; ++nt)
                sb[nt] = *(const short8*)&Ss[nt * 16 + ln][q * 8];
#pragma unroll
            for (int nt = 0; nt < 4; ++nt)
#pragma unroll
                for (int mt = 0; mt < 2; ++mt)
                    at[mt][nt] = __builtin_amdgcn_mfma_f32_16x16x32_bf16(
                        wtf[mt], sb[nt], at[mt][nt], 0, 0, 0);
        }
#pragma unroll
        for (int mt = 0; mt < 2; ++mt)
#pragma unroll
            for (int nt = 0; nt < 4; ++nt) {
                short4v p;
#pragma unroll
                for (int r = 0; r < 4; ++r)
                    p[r] = f2b((a3[mt][nt][r] + biv[mt][r]) * at[mt][nt][r]);
                *(short4v*)&Qs[nt * 16 + ln][mch0 + mt * 16 + q * 4] = p;
            }
        __syncthreads();

        // ---- segmented reduce over the tile (ids sorted, wave-uniform) ----
        // 128 work threads: qsel = Y/Q stream, c2 = channel pair.
        if (tid < 128) {
            const int qsel = tid >> 6;
            const int c2   = tid & 63;
            const short* srcb = qsel ? &Qs[0][0] : &Ys[0][0];
            float* agg = qsel ? agg_q : agg_y;
            float v0 = 0.f, v1 = 0.f;
            int run_start = 0;
            for (int e = 0; e < TE; ++e) {
                const unsigned w = *(const unsigned*)(srcb + e * YLD + 2 * c2);
                union { unsigned u; float f; } lo, hi;
                lo.u = w << 16;
                hi.u = w & 0xFFFF0000u;
                v0 += lo.f;
                v1 += hi.f;
                const int id = ids[e];
                const bool last = (e == TE - 1) || (ids[e + 1] != id);
                if (last) {
                    float* dst = agg + (long)id * Hdim + 2 * c2;
                    if (run_start == 0 || e == TE - 1) {
                        // boundary run: may continue in adjacent tile -> atomic
                        unsafeAtomicAdd(dst, v0);
                        unsafeAtomicAdd(dst + 1, v1);
                    } else {
                        // interior run: globally exclusive writer -> plain store
                        dst[0] = v0;
                        dst[1] = v1;
                    }
                    v0 = 0.f; v1 = 0.f;
                    run_start = e + 1;
                }
            }
        }
        __syncthreads();
    }
}

// ---------------- node kernel ----------------
// h_new    = h + bf16(agg_y) @ W2up + deg*bu2 + b_up
// gate     = sigmoid(h_new @ W_gate + b_gate)
// h_eq_new = h_eq + agg_q * gate
__global__ __launch_bounds__(256, 2)
void ei_node_kernel(const void* __restrict__ hmat,
                    const void* __restrict__ heq,
                    const short* __restrict__ w2up,
                    const float* __restrict__ bu2,
                    const void* __restrict__ bup,
                    const void* __restrict__ Wg,
                    const void* __restrict__ bg,
                    const int*  __restrict__ rs,
                    const float* __restrict__ agg_y,
                    const float* __restrict__ agg_q,
                    void* __restrict__ outp,
                    const int* __restrict__ flags,
                    int N)
{
    __shared__ alignas(16) short Xa[TE][YLD];  // bf16(agg_y) tile
    __shared__ alignas(16) short Yh[TE][YLD];  // bf16(h_new) tile
    __shared__ int degs[TE];

    const int dtf = flags[0];

    const int tid  = threadIdx.x;
    const int lane = tid & 63;
    const int wv   = tid >> 6;
    const int q    = lane >> 4;
    const int ln   = lane & 15;
    const int mch0 = wv * 32;

    short* outh_b = (short*)outp;
    short* outq_b = outh_b + (long)N * Hdim;
    float* outh_f = (float*)outp;
    float* outq_f = outh_f + (long)N * Hdim;

    short8 wcf[4][2], wgf[4][2];
    float4v bu2v[2], bupv[2], bgv[2];
#pragma unroll
    for (int mt = 0; mt < 2; ++mt) {
        const int m = mch0 + mt * 16 + ln;
#pragma unroll
        for (int kc = 0; kc < 4; ++kc) {
            short8 t, u;
            const int k0 = kc * 32 + q * 8;
#pragma unroll
            for (int j = 0; j < 8; ++j) {
                const long idx = (long)(k0 + j) * Hdim + m;
                t[j] = w2up[idx];   // ws, always bf16
                u[j] = dtf ? ((const short*)Wg)[idx] : f2b(((const float*)Wg)[idx]);
            }
            wcf[kc][mt] = t;
            wgf[kc][mt] = u;
        }
        const int cb = mch0 + mt * 16 + q * 4;
#pragma unroll
        for (int r = 0; r < 4; ++r) {
            bu2v[mt][r] = bu2[cb + r];
            bupv[mt][r] = ldf(bup, cb + r, dtf);
            bgv[mt][r]  = ldf(bg, cb + r, dtf);
        }
    }

    const int e_loc = tid >> 2;
    const int part  = tid & 3;
    const int nb    = blockIdx.x * TE;

    // stage bf16(agg_y) tile + degrees
    {
        const int node = nb + e_loc;
        if (node < N) {
            const float4v* src = (const float4v*)(agg_y + (long)node * Hdim + part * 32);
#pragma unroll
            for (int c = 0; c < 4; ++c) {
                const float4v v0 = src[2 * c], v1 = src[2 * c + 1];
                short8 t;
#pragma unroll
                for (int r = 0; r < 4; ++r) { t[r] = f2b(v0[r]); t[4 + r] = f2b(v1[r]); }
                *(short8*)&Xa[e_loc][part * 32 + c * 8] = t;
            }
            if (part == 0) degs[e_loc] = rs[node + 1] - rs[node];
        } else {
            short8 z = {};
#pragma unroll
            for (int c = 0; c < 4; ++c)
                *(short8*)&Xa[e_loc][part * 32 + c * 8] = z;
            if (part == 0) degs[e_loc] = 0;
        }
    }
    __syncthreads();

    // GEMM: agg_y @ W2up ; h_new epilogue
    float4v au[2][4] = {};
#pragma unroll
    for (int kc = 0; kc < 4; ++kc) {
        short8 ab[4];
#pragma unroll
        for (int nt = 0; nt < 4; ++nt)
            ab[nt] = *(const short8*)&Xa[nt * 16 + ln][kc * 32 + q * 8];
#pragma unroll
        for (int nt = 0; nt < 4; ++nt)
#pragma unroll
            for (int mt = 0; mt < 2; ++mt)
                au[mt][nt] = __builtin_amdgcn_mfma_f32_16x16x32_bf16(
                    wcf[kc][mt], ab[nt], au[mt][nt], 0, 0, 0);
    }
#pragma unroll
    for (int mt = 0; mt < 2; ++mt)
#pragma unroll
        for (int nt = 0; nt < 4; ++nt) {
            const int nd = nb + nt * 16 + ln;
            const int ch = mch0 + mt * 16 + q * 4;
            short4v p;
            if (nd < N) {
                const float dg = (float)degs[nt * 16 + ln];
                float hv[4];
                if (dtf) {
                    const short4v x = *(const short4v*)((const short*)hmat + (long)nd * Hdim + ch);
#pragma unroll
                    for (int r = 0; r < 4; ++r) hv[r] = b2f(x[r]);
                } else {
                    const float4v x = *(const float4v*)((const float*)hmat + (long)nd * Hdim + ch);
#pragma unroll
                    for (int r = 0; r < 4; ++r) hv[r] = x[r];
                }
                float4v o;
#pragma unroll
                for (int r = 0; r < 4; ++r) {
                    o[r] = hv[r] + au[mt][nt][r] + dg * bu2v[mt][r] + bupv[mt][r];
                    p[r] = f2b(o[r]);
                }
                if (dtf) *(short4v*)(outh_b + (long)nd * Hdim + ch) = p;
                else     *(float4v*)(outh_f + (long)nd * Hdim + ch) = o;
            } else {
#pragma unroll
                for (int r = 0; r < 4; ++r) p[r] = 0;
            }
            *(short4v*)&Yh[nt * 16 + ln][ch] = p;
        }
    __syncthreads();

    // GEMM: h_new @ W_gate ; h_eq_new epilogue
    float4v ag[2][4] = {};
#pragma unroll
    for (int kc = 0; kc < 4; ++kc) {
        short8 yb[4];
#pragma unroll
        for (int nt = 0; nt < 4; ++nt)
            yb[nt] = *(const short8*)&Yh[nt * 16 + ln][kc * 32 + q * 8];
#pragma unroll
        for (int nt = 0; nt < 4; ++nt)
#pragma unroll
            for (int mt = 0; mt < 2; ++mt)
                ag[mt][nt] = __builtin_amdgcn_mfma_f32_16x16x32_bf16(
                    wgf[kc][mt], yb[nt], ag[mt][nt], 0, 0, 0);
    }
#pragma unroll
    for (int mt = 0; mt < 2; ++mt)
#pragma unroll
        for (int nt = 0; nt < 4; ++nt) {
            const int nd = nb + nt * 16 + ln;
            if (nd >= N) continue;
            const int ch = mch0 + mt * 16 + q * 4;
            const float4v aq = *(const float4v*)(agg_q + (long)nd * Hdim + ch);
            float hev[4];
            if (dtf) {
                const short4v x = *(const short4v*)((const short*)heq + (long)nd * Hdim + ch);
#pragma unroll
                for (int r = 0; r < 4; ++r) hev[r] = b2f(x[r]);
            } else {
                const float4v x = *(const float4v*)((const float*)heq + (long)nd * Hdim + ch);
#pragma unroll
                for (int r = 0; r < 4; ++r) hev[r] = x[r];
            }
            short4v p;
            float4v o;
#pragma unroll
            for (int r = 0; r < 4; ++r) {
                const float g = 1.f / (1.f + __expf(-(ag[mt][nt][r] + bgv[mt][r])));
                o[r] = hev[r] + aq[r] * g;
                p[r] = f2b(o[r]);
            }
            if (dtf) *(short4v*)(outq_b + (long)nd * Hdim + ch) = p;
            else     *(float4v*)(outq_f + (long)nd * Hdim + ch) = o;
        }
}

extern "C" void kernel_launch(void* const* d_in, const int* in_sizes, int n_in,
                              void* d_out, int out_size, void* d_ws, size_t ws_size,
                              hipStream_t stream)
{
    (void)n_in; (void)out_size; (void)ws_size;
    const void* hmat  = d_in[0];
    const void* heq   = d_in[1];
    const void* efeat = d_in[2];
    const void* shm   = d_in[3];
    const void* ei    = d_in[4];
    const void* ej    = d_in[5];
    const void* Win   = d_in[6];
    const void* bin   = d_in[7];
    const void* Wg    = d_in[8];
    const void* bg    = d_in[9];
    const void* W1    = d_in[10];
    const void* b1    = d_in[11];
    const void* W2    = d_in[12];
    const void* b2    = d_in[13];
    const void* Wup   = d_in[14];
    const void* bup   = d_in[15];
    const void* Wtp   = d_in[16];

    const int N = in_sizes[0] / Hdim;
    const int E = in_sizes[2] / Fdim;

    // ws layout (~56 MB)
    auto al = [](size_t x) { return (x + 255) & ~(size_t)255; };
    size_t off = 8;                                   // flags
    off = al(off); const size_t rs_off   = off; off += (size_t)(N + 1) * 4;
    off = al(off); const size_t cur_off  = off; off += (size_t)N * 4;
    off = al(off); const size_t perm_off = off; off += (size_t)E * 4;
    off = al(off); const size_t aggy_off = off; off += (size_t)N * Hdim * 4;
    const size_t aggq_off = off;                     off += (size_t)N * Hdim * 4;
    off = al(off); const size_t w2_off   = off; off += (size_t)Hdim * Hdim * 2;
    off = al(off); const size_t bu2_off  = off; off += (size_t)Hdim * 4;

    char* w = (char*)d_ws;
    int*   flags = (int*)w;
    int*   rs    = (int*)(w + rs_off);
    int*   cur   = (int*)(w + cur_off);
    int*   perm  = (int*)(w + perm_off);
    float* aggy  = (float*)(w + aggy_off);
    float* aggq  = (float*)(w + aggq_off);
    short* w2up  = (short*)(w + w2_off);
    float* bu2   = (float*)(w + bu2_off);

    ei_sniff_kernel<<<1, 64, 0, stream>>>((const unsigned*)hmat, (const unsigned*)ei, flags);
    hipMemsetAsync(cur, 0, (size_t)N * 4, stream);
    hipMemsetAsync(aggy, 0, (size_t)2 * N * Hdim * 4, stream);  // aggy+aggq contiguous
    ei_hist_kernel<<<256, 256, 0, stream>>>(ei, cur, flags, E);
    ei_scan_kernel<<<1, 1024, 0, stream>>>(cur, rs, N, E);
    ei_scatter_kernel<<<256, 256, 0, stream>>>(ei, cur, perm, flags, E);
    ei_w2up_kernel<<<Hdim + 1, Hdim, 0, stream>>>(W2, Wup, b2, w2up, bu2, flags);
    ei_edge_sorted<<<1024, 256, 0, stream>>>(hmat, efeat, shm, ej, perm, (const int*)ei,
                                             W1, b1, Win, bin, Wtp,
                                             aggy, aggq, flags, E / TE);
    ei_node_kernel<<<(N + TE - 1) / TE, 256, 0, stream>>>(
        hmat, heq, w2up, bu2, bup, Wg, bg, rs, aggy, aggq, d_out, flags, N);
}